// Round 10
// baseline (476.815 us; speedup 1.0000x reference)
//
#include <hip/hip_runtime.h>

// Problem constants: B=256, T=256, H=768, S=130
#define BB 256
#define TT 256
#define HH 768
#define SS 130
#define SPAD 160                 // padded S rows per B k-chunk tile
#define NCH 12                   // 768 / 64
#define CHB (SPAD * 128)         // bytes per B chunk tile = 20480
#define REP 6                    // diagnostic amplification

typedef __attribute__((ext_vector_type(8))) __bf16 bf16x8;
typedef __attribute__((ext_vector_type(4))) float f32x4;

__device__ __forceinline__ unsigned f2bf(float f) {
    unsigned x = __builtin_bit_cast(unsigned, f);
    x = (x + 0x7FFFu + ((x >> 16) & 1u)) >> 16;
    return x & 0xFFFFu;
}

// ---- prep: [blocks 0..47] W -> wsT2 swizzled bf16 tiles; [48..303] seg -> bounds ----
__global__ __launch_bounds__(256)
void prep_kernel(const float* __restrict__ W, unsigned* __restrict__ wsT2,
                 const int* __restrict__ seg, int2* __restrict__ bounds)
{
    __shared__ __align__(16) char pm[64 * 41 * 4];
    const int tid = threadIdx.x;

    if (blockIdx.x < 48) {
        float* Wl = (float*)pm;
        const int kc = blockIdx.x >> 2;
        const int qq = blockIdx.x & 3;
        const int sbase = qq * 40;
        const int scv = (SS - sbase < 40) ? (SS - sbase) : 40;
        for (int i = tid; i < 64 * 40; i += 256) {
            int r = i / 40, c = i - r * 40;
            if (c < scv) Wl[r * 41 + c] = W[(size_t)(kc * 64 + r) * SS + sbase + c];
        }
        __syncthreads();
        for (int u = tid; u < 40 * 32; u += 256) {
            int sl = u >> 5, s = sbase + sl, qp = u & 31;
            int ql = (((qp >> 2) ^ (s & 7)) << 2) | (qp & 3);
            unsigned v = 0;
            if (sl < scv)
                v = f2bf(Wl[(2 * ql) * 41 + sl]) | (f2bf(Wl[(2 * ql + 1) * 41 + sl]) << 16);
            wsT2[kc * 5120 + s * 32 + qp] = v;
        }
    } else {
        int* segl = (int*)pm;
        int* st_s = segl + 256;
        int* cn_s = segl + 512;
        const int b = blockIdx.x - 48;
        segl[tid] = seg[b * TT + tid];
        st_s[tid] = 0;
        cn_s[tid] = 0;
        __syncthreads();
        int id = segl[tid];
        if (tid == 0 || segl[tid - 1] != id) {
            int e = tid;
            while (e + 1 < TT && segl[e + 1] == id) ++e;
            st_s[id] = tid;
            cn_s[id] = e - tid + 1;
        }
        __syncthreads();
        bounds[b * TT + tid] = make_int2(st_s[tid], cn_s[tid]);
    }
}

// ---- K1 (production, = R8): B DMA dbuf + vmcnt(4) + 1 barrier/chunk; A direct
// depth-2 named regs. ----
__global__ __launch_bounds__(256, 4)
void gemm_kernel(const float* __restrict__ hidden,
                 const char* __restrict__ wsT2,
                 const float* __restrict__ bias,
                 float* __restrict__ logits)
{
    __shared__ __align__(16) char Blds[2 * CHB];

    const int tid  = threadIdx.x;
    const int wv   = tid >> 6;
    const int lane = tid & 63;
    const int r16  = lane & 15;
    const int g    = lane >> 4;
    const int b    = blockIdx.x >> 2;
    const int tb   = (blockIdx.x & 3) << 6;

    const float* Abase = hidden + (size_t)b * (TT + 1) * HH
                       + (size_t)(1 + tb + wv * 16 + r16) * HH + g * 8;

    f32x4 acc[9];
    #pragma unroll
    for (int j = 0; j < 9; ++j) acc[j] = (f32x4){0.f, 0.f, 0.f, 0.f};

    const int xv = g ^ (r16 & 7);
    const int x0 = xv << 4;
    const int x1 = x0 ^ 64;

    {
        const char* gs = wsT2 + (size_t)wv * 5120 + (size_t)lane * 16;
        unsigned* ld_ = (unsigned*)(Blds + wv * 5120);
        #pragma unroll
        for (int i = 0; i < 5; ++i)
            __builtin_amdgcn_global_load_lds((const unsigned*)(gs + i * 1024),
                                             ld_ + i * 256, 16, 0, 0);
    }
    float4 a00, a01, a02, a03, a10, a11, a12, a13;
    a00 = *(const float4*)(Abase);       a01 = *(const float4*)(Abase + 4);
    a02 = *(const float4*)(Abase + 32);  a03 = *(const float4*)(Abase + 36);
    a10 = *(const float4*)(Abase + 64);  a11 = *(const float4*)(Abase + 68);
    a12 = *(const float4*)(Abase + 96);  a13 = *(const float4*)(Abase + 100);

#define GCHUNK(A0, A1, A2, A3, KC_, PAR_)                                                 \
    do {                                                                                  \
        union { unsigned u[4]; bf16x8 v; } af0u, af1u;                                    \
        asm("v_cvt_pk_bf16_f32 %0, %1, %2" : "=v"(af0u.u[0]) : "v"(A0.x), "v"(A0.y));     \
        asm("v_cvt_pk_bf16_f32 %0, %1, %2" : "=v"(af0u.u[1]) : "v"(A0.z), "v"(A0.w));     \
        asm("v_cvt_pk_bf16_f32 %0, %1, %2" : "=v"(af0u.u[2]) : "v"(A1.x), "v"(A1.y));     \
        asm("v_cvt_pk_bf16_f32 %0, %1, %2" : "=v"(af0u.u[3]) : "v"(A1.z), "v"(A1.w));     \
        asm("v_cvt_pk_bf16_f32 %0, %1, %2" : "=v"(af1u.u[0]) : "v"(A2.x), "v"(A2.y));     \
        asm("v_cvt_pk_bf16_f32 %0, %1, %2" : "=v"(af1u.u[1]) : "v"(A2.z), "v"(A2.w));     \
        asm("v_cvt_pk_bf16_f32 %0, %1, %2" : "=v"(af1u.u[2]) : "v"(A3.x), "v"(A3.y));     \
        asm("v_cvt_pk_bf16_f32 %0, %1, %2" : "=v"(af1u.u[3]) : "v"(A3.z), "v"(A3.w));     \
        asm volatile("s_waitcnt vmcnt(4)" ::: "memory");                                  \
        __builtin_amdgcn_s_barrier();                                                     \
        __builtin_amdgcn_sched_barrier(0);                                                \
        {                                                                                 \
            const int kb_ = ((KC_) + 1 < NCH) ? (KC_) + 1 : NCH - 1;                      \
            const char* gs_ = wsT2 + (size_t)kb_ * CHB + (size_t)wv * 5120 + (size_t)lane * 16; \
            unsigned* ld_ = (unsigned*)(Blds + (1 - (PAR_)) * CHB + wv * 5120);           \
            _Pragma("unroll")                                                             \
            for (int i_ = 0; i_ < 5; ++i_)                                                \
                __builtin_amdgcn_global_load_lds((const unsigned*)(gs_ + i_ * 1024),      \
                                                 ld_ + i_ * 256, 16, 0, 0);               \
        }                                                                                 \
        {                                                                                 \
            const int ka_ = ((KC_) + 2 < NCH) ? (KC_) + 2 : NCH - 1;                      \
            const float* ap_ = Abase + ka_ * 64;                                          \
            A0 = *(const float4*)(ap_);       A1 = *(const float4*)(ap_ + 4);             \
            A2 = *(const float4*)(ap_ + 32);  A3 = *(const float4*)(ap_ + 36);            \
        }                                                                                 \
        __builtin_amdgcn_sched_barrier(0);                                                \
        {                                                                                 \
            const char* base_ = Blds + (PAR_) * CHB + r16 * 128;                          \
            _Pragma("unroll")                                                             \
            for (int nt = 0; nt < 9; ++nt)                                                \
                acc[nt] = __builtin_amdgcn_mfma_f32_16x16x32_bf16(                        \
                    af0u.v, *(const bf16x8*)(base_ + nt * 2048 + x0), acc[nt], 0, 0, 0);  \
            _Pragma("unroll")                                                             \
            for (int nt = 0; nt < 9; ++nt)                                                \
                acc[nt] = __builtin_amdgcn_mfma_f32_16x16x32_bf16(                        \
                    af1u.v, *(const bf16x8*)(base_ + nt * 2048 + x1), acc[nt], 0, 0, 0);  \
        }                                                                                 \
    } while (0)

    #pragma unroll 1
    for (int kp = 0; kp < NCH / 2; ++kp) {
        GCHUNK(a00, a01, a02, a03, 2 * kp, 0);
        GCHUNK(a10, a11, a12, a13, 2 * kp + 1, 1);
    }
#undef GCHUNK

    asm volatile("s_waitcnt vmcnt(0)" ::: "memory");

    const int tq = tb + wv * 16 + g * 4;
    #pragma unroll
    for (int nt = 0; nt < 9; ++nt) {
        int s = nt * 16 + r16;
        if (s < SS) {
            float bs = bias[s];
            float4 v = make_float4(acc[nt][0] + bs, acc[nt][1] + bs,
                                   acc[nt][2] + bs, acc[nt][3] + bs);
            *(float4*)(logits + ((size_t)b * SS + s) * TT + tq) = v;
        }
    }
}

// ---- K2 (production, = R8): barrier-free ragged segment-mean ----
__global__ __launch_bounds__(256)
void merge_kernel(const int2* __restrict__ bounds,
                  const float* __restrict__ logits,
                  float* __restrict__ out)
{
    const int blk = blockIdx.x;
    const int b   = blk / 65;
    const int sp  = (blk - b * 65) * 2;
    const int w   = threadIdx.x;

    const int2 bc = bounds[b * TT + w];
    const float inv = (bc.y > 0) ? 1.f / (float)bc.y : 0.f;

    #pragma unroll
    for (int i = 0; i < 2; ++i) {
        const int s = sp + i;
        const float* row = logits + ((size_t)b * SS + s) * TT;
        float a = 0.f;
        for (int k = 0; k < bc.y; ++k) a += row[bc.x + k];
        out[((size_t)b * SS + s) * TT + w] = a * inv;
    }
}

// ---- diag_a: A-path only (scatter loads + cvt + MFMA vs opaque B), x6 ----
__global__ __launch_bounds__(256, 4)
void diag_a_kernel(const float* __restrict__ hidden, const float* __restrict__ bias,
                   float* __restrict__ dummy)
{
    __shared__ __align__(16) char Blds[2 * CHB];
    const int tid  = threadIdx.x;
    const int wv   = tid >> 6;
    const int lane = tid & 63;
    const int r16  = lane & 15;
    const int g    = lane >> 4;
    const int b    = blockIdx.x >> 2;
    const int tb   = (blockIdx.x & 3) << 6;
    if (tid == 0) ((volatile int*)Blds)[0] = 0;   // keep LDS footprint = gemm's

    const float* Abase = hidden + (size_t)b * (TT + 1) * HH
                       + (size_t)(1 + tb + wv * 16 + r16) * HH + g * 8;

    f32x4 acc[9];
    #pragma unroll
    for (int j = 0; j < 9; ++j) acc[j] = (f32x4){0.f, 0.f, 0.f, 0.f};

    union { unsigned u[4]; bf16x8 v; } bc;
    bc.u[0] = __builtin_bit_cast(unsigned, bias[r16]);
    bc.u[1] = bc.u[0] + 1; bc.u[2] = bc.u[0] + 2; bc.u[3] = bc.u[0] + 3;
    asm volatile("" : "+v"(bc.u[0]), "+v"(bc.u[1]), "+v"(bc.u[2]), "+v"(bc.u[3]));

#define DACHUNK(A0, A1, A2, A3, KC_)                                                      \
    do {                                                                                  \
        union { unsigned u[4]; bf16x8 v; } af0_, af1_;                                    \
        asm("v_cvt_pk_bf16_f32 %0, %1, %2" : "=v"(af0_.u[0]) : "v"(A0.x), "v"(A0.y));     \
        asm("v_cvt_pk_bf16_f32 %0, %1, %2" : "=v"(af0_.u[1]) : "v"(A0.z), "v"(A0.w));     \
        asm("v_cvt_pk_bf16_f32 %0, %1, %2" : "=v"(af0_.u[2]) : "v"(A1.x), "v"(A1.y));     \
        asm("v_cvt_pk_bf16_f32 %0, %1, %2" : "=v"(af0_.u[3]) : "v"(A1.z), "v"(A1.w));     \
        asm("v_cvt_pk_bf16_f32 %0, %1, %2" : "=v"(af1_.u[0]) : "v"(A2.x), "v"(A2.y));     \
        asm("v_cvt_pk_bf16_f32 %0, %1, %2" : "=v"(af1_.u[1]) : "v"(A2.z), "v"(A2.w));     \
        asm("v_cvt_pk_bf16_f32 %0, %1, %2" : "=v"(af1_.u[2]) : "v"(A3.x), "v"(A3.y));     \
        asm("v_cvt_pk_bf16_f32 %0, %1, %2" : "=v"(af1_.u[3]) : "v"(A3.z), "v"(A3.w));     \
        { const int ka_ = ((KC_) + 2 < NCH) ? (KC_) + 2 : NCH - 1;                        \
          const float* ap_ = Abase + ka_ * 64;                                            \
          A0 = *(const float4*)(ap_);       A1 = *(const float4*)(ap_ + 4);               \
          A2 = *(const float4*)(ap_ + 32);  A3 = *(const float4*)(ap_ + 36); }            \
        _Pragma("unroll")                                                                 \
        for (int nt = 0; nt < 9; ++nt)                                                    \
            acc[nt] = __builtin_amdgcn_mfma_f32_16x16x32_bf16(af0_.v, bc.v, acc[nt], 0, 0, 0); \
        _Pragma("unroll")                                                                 \
        for (int nt = 0; nt < 9; ++nt)                                                    \
            acc[nt] = __builtin_amdgcn_mfma_f32_16x16x32_bf16(af1_.v, bc.v, acc[nt], 0, 0, 0); \
    } while (0)

    #pragma unroll 1
    for (int rep = 0; rep < REP; ++rep) {
        float4 e0, e1, e2, e3, o0, o1, o2, o3;
        e0 = *(const float4*)(Abase);       e1 = *(const float4*)(Abase + 4);
        e2 = *(const float4*)(Abase + 32);  e3 = *(const float4*)(Abase + 36);
        o0 = *(const float4*)(Abase + 64);  o1 = *(const float4*)(Abase + 68);
        o2 = *(const float4*)(Abase + 96);  o3 = *(const float4*)(Abase + 100);
        #pragma unroll 1
        for (int kp = 0; kp < NCH / 2; ++kp) {
            DACHUNK(e0, e1, e2, e3, 2 * kp);
            DACHUNK(o0, o1, o2, o3, 2 * kp + 1);
        }
    }
#undef DACHUNK

    const int tq = tb + wv * 16 + g * 4;
    #pragma unroll
    for (int nt = 0; nt < 9; ++nt) {
        int s = nt * 16 + r16;
        if (s < SS)
            *(float4*)(dummy + ((size_t)b * SS + s) * TT + tq) =
                make_float4(acc[nt][0], acc[nt][1], acc[nt][2], acc[nt][3]);
    }
}

// ---- diag_b: B-path only (DMA dbuf + vmcnt + barrier + ds_read + MFMA vs opaque A), x6 ----
__global__ __launch_bounds__(256, 4)
void diag_b_kernel(const char* __restrict__ wsT2, const float* __restrict__ bias,
                   float* __restrict__ dummy)
{
    __shared__ __align__(16) char Blds[2 * CHB];
    const int tid  = threadIdx.x;
    const int wv   = tid >> 6;
    const int lane = tid & 63;
    const int r16  = lane & 15;
    const int g    = lane >> 4;
    const int b    = blockIdx.x >> 2;
    const int tb   = (blockIdx.x & 3) << 6;

    f32x4 acc[9];
    #pragma unroll
    for (int j = 0; j < 9; ++j) acc[j] = (f32x4){0.f, 0.f, 0.f, 0.f};

    union { unsigned u[4]; bf16x8 v; } afc;
    afc.u[0] = __builtin_bit_cast(unsigned, bias[r16]);
    afc.u[1] = afc.u[0] + 1; afc.u[2] = afc.u[0] + 2; afc.u[3] = afc.u[0] + 3;
    asm volatile("" : "+v"(afc.u[0]), "+v"(afc.u[1]), "+v"(afc.u[2]), "+v"(afc.u[3]));

    const int xv = g ^ (r16 & 7);
    const int x0 = xv << 4;
    const int x1 = x0 ^ 64;

#define DBDMA(KB_, PAR_)                                                                  \
    do { const char* gs_ = wsT2 + (size_t)(KB_) * CHB + (size_t)wv * 5120 + (size_t)lane * 16; \
         unsigned* ld_ = (unsigned*)(Blds + (PAR_) * CHB + wv * 5120);                    \
         _Pragma("unroll")                                                                \
         for (int i_ = 0; i_ < 5; ++i_)                                                   \
             __builtin_amdgcn_global_load_lds((const unsigned*)(gs_ + i_ * 1024),         \
                                              ld_ + i_ * 256, 16, 0, 0); } while (0)

#define DBCHUNK(KC_, PAR_)                                                                \
    do {                                                                                  \
        asm volatile("s_waitcnt vmcnt(0)" ::: "memory");                                  \
        __builtin_amdgcn_s_barrier();                                                     \
        { const int kb_ = ((KC_) + 1 < NCH) ? (KC_) + 1 : NCH - 1; DBDMA(kb_, 1 - (PAR_)); } \
        { const char* base_ = Blds + (PAR_) * CHB + r16 * 128;                            \
          _Pragma("unroll")                                                               \
          for (int nt = 0; nt < 9; ++nt) {                                                \
              bf16x8 b0_ = *(const bf16x8*)(base_ + nt * 2048 + x0);                      \
              acc[nt] = __builtin_amdgcn_mfma_f32_16x16x32_bf16(afc.v, b0_, acc[nt], 0, 0, 0); } \
          _Pragma("unroll")                                                               \
          for (int nt = 0; nt < 9; ++nt) {                                                \
              bf16x8 b1_ = *(const bf16x8*)(base_ + nt * 2048 + x1);                      \
              acc[nt] = __builtin_amdgcn_mfma_f32_16x16x32_bf16(afc.v, b1_, acc[nt], 0, 0, 0); } \
        }                                                                                 \
    } while (0)

    #pragma unroll 1
    for (int rep = 0; rep < REP; ++rep) {
        DBDMA(0, 0);
        #pragma unroll 1
        for (int kp = 0; kp < NCH / 2; ++kp) {
            DBCHUNK(2 * kp, 0);
            DBCHUNK(2 * kp + 1, 1);
        }
    }
#undef DBCHUNK
#undef DBDMA

    asm volatile("s_waitcnt vmcnt(0)" ::: "memory");

    const int tq = tb + wv * 16 + g * 4;
    #pragma unroll
    for (int nt = 0; nt < 9; ++nt) {
        int s = nt * 16 + r16;
        if (s < SS)
            *(float4*)(dummy + ((size_t)b * SS + s) * TT + tq) =
                make_float4(acc[nt][0], acc[nt][1], acc[nt][2], acc[nt][3]);
    }
}

// ---- diag_c: same A bytes, PURE SEQUENTIAL per-block stream (fill-like), x6 ----
__global__ __launch_bounds__(256, 4)
void diag_c_kernel(const float* __restrict__ hidden, float* __restrict__ dummy)
{
    __shared__ __align__(16) char Blds[2 * CHB];
    const int tid = threadIdx.x;
    if (tid == 0) ((volatile int*)Blds)[0] = 0;   // same residency as gemm
    const int b  = blockIdx.x >> 2;
    const int tb = (blockIdx.x & 3) << 6;
    const float4* base = (const float4*)(hidden + (size_t)b * (TT + 1) * HH
                                         + (size_t)(1 + tb) * HH);
    float4 s4 = make_float4(0.f, 0.f, 0.f, 0.f);
    #pragma unroll 1
    for (int rep = 0; rep < REP; ++rep) {
        #pragma unroll 8
        for (int i = 0; i < 48; ++i) {            // 48 x 256 lanes x 16B = 192 KB/block
            float4 v = base[(size_t)i * 256 + tid];
            s4.x += v.x; s4.y += v.y; s4.z += v.z; s4.w += v.w;
        }
    }
    dummy[(size_t)blockIdx.x * 256 + tid] = s4.x + s4.y + s4.z + s4.w;
}

extern "C" void kernel_launch(void* const* d_in, const int* in_sizes, int n_in,
                              void* d_out, int out_size, void* d_ws, size_t ws_size,
                              hipStream_t stream)
{
    const float* hidden = (const float*)d_in[0];  // [256, 257, 768] f32
    const float* W      = (const float*)d_in[1];  // [768, 130] f32
    const float* bias   = (const float*)d_in[2];  // [130] f32
    const int*   seg    = (const int*)d_in[3];    // [256, 256] i32 (row-sorted)
    float* out = (float*)d_out;                   // [256, 130, 256] f32

    unsigned* wsT2   = (unsigned*)d_ws;                                   // 245760 B
    int2*     bounds = (int2*)((char*)d_ws + 245760);                     // 524288 B
    float*    logits = (float*)((char*)d_ws + 245760 + 524288);           // 34078720 B
    float*    dummy  = (float*)((char*)d_ws + 245760 + 524288 + 34078720);// 34078720 B

    (void)in_sizes; (void)n_in; (void)ws_size; (void)out_size;

    prep_kernel<<<dim3(304), dim3(256), 0, stream>>>(W, wsT2, seg, bounds);
    gemm_kernel<<<dim3(BB * 4), dim3(256), 0, stream>>>(hidden, (const char*)wsT2, bias, logits);
    merge_kernel<<<dim3(BB * 65), dim3(256), 0, stream>>>(bounds, logits, out);

    // diagnostics (write to dummy; amplified x6 to clear the ~113 us fill bar)
    diag_a_kernel<<<dim3(BB * 4), dim3(256), 0, stream>>>(hidden, bias, dummy);
    diag_b_kernel<<<dim3(BB * 4), dim3(256), 0, stream>>>((const char*)wsT2, bias, dummy);
    diag_c_kernel<<<dim3(BB * 4), dim3(256), 0, stream>>>(hidden, dummy);
}

// Round 11
// 358.596 us; speedup vs baseline: 1.3297x; 1.3297x over previous
//
#include <hip/hip_runtime.h>

// Problem constants: B=256, T=256, H=768, S=130
#define BB 256
#define TT 256
#define HH 768
#define SS 130
#define NPH 6                    // K phases of 128
#define SLU 10240                // uints per wsT2 phase slice (160 rows x 64 uints = 40960 B)

typedef __attribute__((ext_vector_type(8))) __bf16 bf16x8;
typedef __attribute__((ext_vector_type(4))) float f32x4;

__device__ __forceinline__ unsigned f2bf(float f) {
    unsigned x = __builtin_bit_cast(unsigned, f);
    x = (x + 0x7FFFu + ((x >> 16) & 1u)) >> 16;
    return x & 0xFFFFu;
}

// ---- prep: [0..47] W -> wsT2 [6][160 s][128 k bf16], 16B-slot j stored at j^(s&15);
//            [48..303] seg -> bounds {start,count} ----
__global__ __launch_bounds__(256)
void prep_kernel(const float* __restrict__ W, unsigned* __restrict__ wsT2,
                 const int* __restrict__ seg, int2* __restrict__ bounds)
{
    __shared__ __align__(16) char pm[128 * 21 * 4];   // 10752 B
    const int tid = threadIdx.x;

    if (blockIdx.x < 48) {
        float* Wl = (float*)pm;                        // [128 k][21]
        const int kc6   = blockIdx.x >> 3;             // phase 0..5
        const int g20   = blockIdx.x & 7;              // s-group of 20
        const int sbase = g20 * 20;
        const int scv   = SS - sbase;                  // valid cols (may be <=0)
        for (int i = tid; i < 128 * 20; i += 256) {
            int r = i / 20, c = i - r * 20;
            float v = 0.f;
            if (c < scv) v = W[(size_t)(kc6 * 128 + r) * SS + sbase + c];
            Wl[r * 21 + c] = v;
        }
        __syncthreads();
        for (int i = tid; i < 20 * 64; i += 256) {     // coalesced 256B-row writes
            int sl = i >> 6, qu = i & 63;
            int s  = sbase + sl;
            int qp = qu >> 2, m = qu & 3;
            int j  = qp ^ (s & 15);                    // logical 16B slot
            int kp = j * 4 + m;                        // k-pair 0..63 within slice
            unsigned v = 0;
            if (sl < scv)
                v = f2bf(Wl[(2 * kp) * 21 + sl]) | (f2bf(Wl[(2 * kp + 1) * 21 + sl]) << 16);
            wsT2[kc6 * SLU + s * 64 + qu] = v;
        }
    } else {
        int* segl = (int*)pm;
        int* st_s = segl + 256;
        int* cn_s = segl + 512;
        const int b = blockIdx.x - 48;
        segl[tid] = seg[b * TT + tid];
        st_s[tid] = 0;
        cn_s[tid] = 0;
        __syncthreads();
        int id = segl[tid];
        if (tid == 0 || segl[tid - 1] != id) {
            int e = tid;
            while (e + 1 < TT && segl[e + 1] == id) ++e;
            st_s[id] = tid;
            cn_s[id] = e - tid + 1;
        }
        __syncthreads();
        bounds[b * TT + tid] = make_int2(st_s[tid], cn_s[tid]);
    }
}

// ================= GEMM body (shared by production + x4 clone) =================
#define GEMM_DECLS                                                                        \
    const int tid  = threadIdx.x;                                                        \
    const int wv   = tid >> 6;                                                           \
    const int lane = tid & 63;                                                           \
    const int r16  = lane & 15;                                                          \
    const int g    = lane >> 4;                                                          \
    const int b    = blockIdx.x >> 2;                                                    \
    const int tb   = (blockIdx.x & 3) << 6;                                              \
    const float* Abase = hidden + (size_t)b * (TT + 1) * HH                              \
                       + (size_t)(1 + tb + wv * 16 + r16) * HH + g * 8;

#define DMA6(P)                                                                           \
    do {                                                                                  \
        const unsigned* gs_ = wsT2 + (size_t)(P) * SLU + wv * 2560 + lane * 4;            \
        unsigned* ld_ = Blds + wv * 2560;                                                 \
        _Pragma("unroll")                                                                 \
        for (int i_ = 0; i_ < 10; ++i_)                                                   \
            __builtin_amdgcn_global_load_lds(gs_ + i_ * 256, ld_ + i_ * 256, 16, 0, 0);   \
    } while (0)

#define LOADA(X0, X1, X2, X3, X4, X5, X6, X7, P)                                          \
    do {                                                                                  \
        const float* ap_ = Abase + (P) * 128;                                             \
        X0 = *(const float4*)(ap_);        X1 = *(const float4*)(ap_ + 4);                \
        X2 = *(const float4*)(ap_ + 32);   X3 = *(const float4*)(ap_ + 36);               \
        X4 = *(const float4*)(ap_ + 64);   X5 = *(const float4*)(ap_ + 68);               \
        X6 = *(const float4*)(ap_ + 96);   X7 = *(const float4*)(ap_ + 100);              \
    } while (0)

#define CHUNKC(Ea, Eb, C_)                                                                \
    do {                                                                                  \
        union { unsigned u[4]; bf16x8 v; } af_;                                           \
        asm("v_cvt_pk_bf16_f32 %0, %1, %2" : "=v"(af_.u[0]) : "v"(Ea.x), "v"(Ea.y));      \
        asm("v_cvt_pk_bf16_f32 %0, %1, %2" : "=v"(af_.u[1]) : "v"(Ea.z), "v"(Ea.w));      \
        asm("v_cvt_pk_bf16_f32 %0, %1, %2" : "=v"(af_.u[2]) : "v"(Eb.x), "v"(Eb.y));      \
        asm("v_cvt_pk_bf16_f32 %0, %1, %2" : "=v"(af_.u[3]) : "v"(Eb.z), "v"(Eb.w));      \
        const char* bp_ = (const char*)Blds + r16 * 256 + ((((C_) * 4 + g) ^ r16) << 4);  \
        _Pragma("unroll")                                                                 \
        for (int nt = 0; nt < 9; ++nt)                                                    \
            acc[nt] = __builtin_amdgcn_mfma_f32_16x16x32_bf16(                            \
                af_.v, *(const bf16x8*)(bp_ + nt * 4096), acc[nt], 0, 0, 0);              \
    } while (0)

// one K=128 phase: drain -> DMA -> wait -> barrier -> prefetch next A -> 4 free chunks
#define PHASE(C0, C1, C2, C3, C4, C5, C6, C7, N0, N1, N2, N3, N4, N5, N6, N7, P)          \
    do {                                                                                  \
        __syncthreads();                                                                  \
        DMA6(P);                                                                          \
        asm volatile("s_waitcnt vmcnt(0)" ::: "memory");                                  \
        __syncthreads();                                                                  \
        { const int pn_ = ((P) + 1 < NPH) ? (P) + 1 : NPH - 1;                            \
          LOADA(N0, N1, N2, N3, N4, N5, N6, N7, pn_); }                                   \
        CHUNKC(C0, C1, 0); CHUNKC(C2, C3, 1); CHUNKC(C4, C5, 2); CHUNKC(C6, C7, 3);       \
    } while (0)

#define GEMM_LOOP                                                                         \
    float4 e0, e1, e2, e3, e4, e5, e6, e7;                                                \
    float4 o0, o1, o2, o3, o4, o5, o6, o7;                                                \
    LOADA(e0, e1, e2, e3, e4, e5, e6, e7, 0);                                             \
    _Pragma("unroll 1")                                                                   \
    for (int pp = 0; pp < 3; ++pp) {                                                      \
        PHASE(e0, e1, e2, e3, e4, e5, e6, e7, o0, o1, o2, o3, o4, o5, o6, o7, 2 * pp);    \
        PHASE(o0, o1, o2, o3, o4, o5, o6, o7, e0, e1, e2, e3, e4, e5, e6, e7, 2 * pp + 1);\
    }

#define GEMM_EPI(DST)                                                                     \
    do {                                                                                  \
        const int tq = tb + wv * 16 + g * 4;                                              \
        _Pragma("unroll")                                                                 \
        for (int nt = 0; nt < 9; ++nt) {                                                  \
            int s = nt * 16 + r16;                                                        \
            if (s < SS) {                                                                 \
                float bs = bias[s];                                                       \
                float4 v = make_float4(acc[nt][0] + bs, acc[nt][1] + bs,                  \
                                       acc[nt][2] + bs, acc[nt][3] + bs);                 \
                *(float4*)((DST) + ((size_t)b * SS + s) * TT + tq) = v;                   \
            }                                                                             \
        }                                                                                 \
    } while (0)

// ---- K1 production: 6-phase single-buffer GEMM ----
__global__ __launch_bounds__(256, 4)
void gemm_kernel(const float* __restrict__ hidden, const unsigned* __restrict__ wsT2,
                 const float* __restrict__ bias, float* __restrict__ logits)
{
    __shared__ __align__(16) unsigned Blds[SLU];   // 40960 B -> exactly 4 blocks/CU
    GEMM_DECLS
    f32x4 acc[9];
    #pragma unroll
    for (int j = 0; j < 9; ++j) acc[j] = (f32x4){0.f, 0.f, 0.f, 0.f};
    GEMM_LOOP
    GEMM_EPI(logits);
}

// ---- diagnostic clone: same GEMM x4 into dummy (non-restrict => reps not CSE'd) ----
__global__ __launch_bounds__(256, 4)
void gemm_x4_kernel(const float* hidden, const unsigned* wsT2,
                    const float* bias, float* dummy)
{
    __shared__ __align__(16) unsigned Blds[SLU];
    GEMM_DECLS
    f32x4 acc[9];
    #pragma unroll
    for (int j = 0; j < 9; ++j) acc[j] = (f32x4){0.f, 0.f, 0.f, 0.f};
    #pragma unroll 1
    for (int rep = 0; rep < 4; ++rep) {
        GEMM_LOOP
    }
    GEMM_EPI(dummy);
}

// ---- K2 production: barrier-free ragged segment-mean ----
__global__ __launch_bounds__(256)
void merge_kernel(const int2* __restrict__ bounds,
                  const float* __restrict__ logits,
                  float* __restrict__ out)
{
    const int blk = blockIdx.x;
    const int b   = blk / 65;
    const int sp  = (blk - b * 65) * 2;
    const int w   = threadIdx.x;

    const int2 bc = bounds[b * TT + w];
    const float inv = (bc.y > 0) ? 1.f / (float)bc.y : 0.f;

    #pragma unroll
    for (int i = 0; i < 2; ++i) {
        const int s = sp + i;
        const float* row = logits + ((size_t)b * SS + s) * TT;
        float a = 0.f;
        for (int k = 0; k < bc.y; ++k) a += row[bc.x + k];
        out[((size_t)b * SS + s) * TT + w] = a * inv;
    }
}

// ---- diagnostic clone: merge x8 into dummy (non-restrict) ----
__global__ __launch_bounds__(256)
void merge_x8_kernel(const int2* bounds, const float* logits, float* dummy)
{
    const int blk = blockIdx.x;
    const int b   = blk / 65;
    const int sp  = (blk - b * 65) * 2;
    const int w   = threadIdx.x;

    #pragma unroll 1
    for (int rep = 0; rep < 8; ++rep) {
        const int2 bc = bounds[b * TT + w];
        const float inv = (bc.y > 0) ? 1.f / (float)bc.y : 0.f;
        #pragma unroll
        for (int i = 0; i < 2; ++i) {
            const int s = sp + i;
            const float* row = logits + ((size_t)b * SS + s) * TT;
            float a = 0.f;
            for (int k = 0; k < bc.y; ++k) a += row[bc.x + k];
            dummy[((size_t)b * SS + s) * TT + w] = a * inv;
        }
    }
}

extern "C" void kernel_launch(void* const* d_in, const int* in_sizes, int n_in,
                              void* d_out, int out_size, void* d_ws, size_t ws_size,
                              hipStream_t stream)
{
    const float* hidden = (const float*)d_in[0];  // [256, 257, 768] f32
    const float* W      = (const float*)d_in[1];  // [768, 130] f32
    const float* bias   = (const float*)d_in[2];  // [130] f32
    const int*   seg    = (const int*)d_in[3];    // [256, 256] i32 (row-sorted)
    float* out = (float*)d_out;                   // [256, 130, 256] f32

    unsigned* wsT2   = (unsigned*)d_ws;                                    // 245760 B
    int2*     bounds = (int2*)((char*)d_ws + 245760);                      // 524288 B
    float*    logits = (float*)((char*)d_ws + 245760 + 524288);            // 34078720 B
    float*    dummy  = (float*)((char*)d_ws + 245760 + 524288 + 34078720); // 34078720 B

    (void)in_sizes; (void)n_in; (void)ws_size; (void)out_size;

    prep_kernel<<<dim3(304), dim3(256), 0, stream>>>(W, wsT2, seg, bounds);
    gemm_kernel<<<dim3(BB * 4), dim3(256), 0, stream>>>(hidden, wsT2, bias, logits);
    merge_kernel<<<dim3(BB * 65), dim3(256), 0, stream>>>(bounds, logits, out);

    // amplified diagnostics (write dummy; clear the ~113 us fill bar for counters)
    gemm_x4_kernel<<<dim3(BB * 4), dim3(256), 0, stream>>>(hidden, wsT2, bias, dummy);
    merge_x8_kernel<<<dim3(BB * 65), dim3(256), 0, stream>>>(bounds, logits, dummy);
}

// Round 12
// 79.959 us; speedup vs baseline: 5.9633x; 4.4848x over previous
//
#include <hip/hip_runtime.h>

// Problem constants: B=256, T=256, H=768, S=130
#define BB 256
#define TT 256
#define HH 768
#define SS 130
#define NPH 6                    // K phases of 128
#define SROWS 144                // 9 n-tiles x 16 rows per B slice
#define SLU (SROWS * 64)         // uints per wsT2 phase slice = 9216 (36864 B)

typedef __attribute__((ext_vector_type(8))) __bf16 bf16x8;
typedef __attribute__((ext_vector_type(4))) float f32x4;

__device__ __forceinline__ unsigned f2bf(float f) {
    unsigned x = __builtin_bit_cast(unsigned, f);
    x = (x + 0x7FFFu + ((x >> 16) & 1u)) >> 16;
    return x & 0xFFFFu;
}
__device__ __forceinline__ float bf2f(unsigned short u) {
    return __builtin_bit_cast(float, (unsigned)u << 16);
}

// ---- prep: [0..53] W -> wsT2 [6][144 s][128 k bf16], 16B-slot j at j^(s&15);
//            [54..309] seg -> bounds {start,count} ----
__global__ __launch_bounds__(256)
void prep_kernel(const float* __restrict__ W, unsigned* __restrict__ wsT2,
                 const int* __restrict__ seg, int2* __restrict__ bounds)
{
    __shared__ __align__(16) char pm[128 * 17 * 4];   // 8704 B
    const int tid = threadIdx.x;

    if (blockIdx.x < 54) {
        float* Wl = (float*)pm;                        // [128 k][17]
        const int kc6   = blockIdx.x / 9;              // phase 0..5
        const int g16   = blockIdx.x % 9;              // s-group of 16
        const int sbase = g16 * 16;
        const int scv   = (SS - sbase < 16) ? (SS - sbase) : 16;  // may be <=0 handled by c<scv
        for (int i = tid; i < 128 * 16; i += 256) {
            int r = i >> 4, c = i & 15;
            float v = 0.f;
            if (c < scv) v = W[(size_t)(kc6 * 128 + r) * SS + sbase + c];
            Wl[r * 17 + c] = v;
        }
        __syncthreads();
        for (int i = tid; i < 16 * 64; i += 256) {     // coalesced 256B-row writes
            int sl = i >> 6, qu = i & 63;
            int s  = sbase + sl;
            int qp = qu >> 2, m = qu & 3;
            int j  = qp ^ (s & 15);                    // logical 16B slot (involution)
            int kp = j * 4 + m;                        // k-pair 0..63 within slice
            unsigned v = 0;
            if (sl < scv)
                v = f2bf(Wl[(2 * kp) * 17 + sl]) | (f2bf(Wl[(2 * kp + 1) * 17 + sl]) << 16);
            wsT2[kc6 * SLU + s * 64 + qu] = v;
        }
    } else {
        int* segl = (int*)pm;
        int* st_s = segl + 256;
        int* cn_s = segl + 512;
        const int b = blockIdx.x - 54;
        segl[tid] = seg[b * TT + tid];
        st_s[tid] = 0;
        cn_s[tid] = 0;
        __syncthreads();
        int id = segl[tid];
        if (tid == 0 || segl[tid - 1] != id) {         // run starts (seg row-sorted)
            int e = tid;
            while (e + 1 < TT && segl[e + 1] == id) ++e;
            st_s[id] = tid;
            cn_s[id] = e - tid + 1;
        }
        __syncthreads();
        bounds[b * TT + tid] = make_int2(st_s[tid], cn_s[tid]);
    }
}

// ---- K1: 6-phase single-buffer GEMM (R11 structure, 144-row B slices, bf16 out) ----
__global__ __launch_bounds__(256, 4)
void gemm_kernel(const float* __restrict__ hidden, const unsigned* __restrict__ wsT2,
                 const float* __restrict__ bias, unsigned short* __restrict__ logits)
{
    __shared__ __align__(16) unsigned Blds[SLU];       // 36864 B -> 4 blocks/CU

    const int tid  = threadIdx.x;
    const int wv   = tid >> 6;
    const int lane = tid & 63;
    const int r16  = lane & 15;
    const int g    = lane >> 4;
    const int b    = blockIdx.x >> 2;
    const int tb   = (blockIdx.x & 3) << 6;
    const float* Abase = hidden + (size_t)b * (TT + 1) * HH
                       + (size_t)(1 + tb + wv * 16 + r16) * HH + g * 8;

    f32x4 acc[9];
    #pragma unroll
    for (int j = 0; j < 9; ++j) acc[j] = (f32x4){0.f, 0.f, 0.f, 0.f};

#define DMA9(P)                                                                           \
    do {                                                                                  \
        const unsigned* gs_ = wsT2 + (size_t)(P) * SLU + wv * 2304 + lane * 4;            \
        unsigned* ld_ = Blds + wv * 2304;                                                 \
        _Pragma("unroll")                                                                 \
        for (int i_ = 0; i_ < 9; ++i_)                                                    \
            __builtin_amdgcn_global_load_lds(gs_ + i_ * 256, ld_ + i_ * 256, 16, 0, 0);   \
    } while (0)

#define LOADA(X0, X1, X2, X3, X4, X5, X6, X7, P)                                          \
    do {                                                                                  \
        const float* ap_ = Abase + (P) * 128;                                             \
        X0 = *(const float4*)(ap_);        X1 = *(const float4*)(ap_ + 4);                \
        X2 = *(const float4*)(ap_ + 32);   X3 = *(const float4*)(ap_ + 36);               \
        X4 = *(const float4*)(ap_ + 64);   X5 = *(const float4*)(ap_ + 68);               \
        X6 = *(const float4*)(ap_ + 96);   X7 = *(const float4*)(ap_ + 100);              \
    } while (0)

#define CHUNKC(Ea, Eb, C_)                                                                \
    do {                                                                                  \
        union { unsigned u[4]; bf16x8 v; } af_;                                           \
        asm("v_cvt_pk_bf16_f32 %0, %1, %2" : "=v"(af_.u[0]) : "v"(Ea.x), "v"(Ea.y));      \
        asm("v_cvt_pk_bf16_f32 %0, %1, %2" : "=v"(af_.u[1]) : "v"(Ea.z), "v"(Ea.w));      \
        asm("v_cvt_pk_bf16_f32 %0, %1, %2" : "=v"(af_.u[2]) : "v"(Eb.x), "v"(Eb.y));      \
        asm("v_cvt_pk_bf16_f32 %0, %1, %2" : "=v"(af_.u[3]) : "v"(Eb.z), "v"(Eb.w));      \
        const char* bp_ = (const char*)Blds + r16 * 256 + ((((C_) * 4 + g) ^ r16) << 4);  \
        _Pragma("unroll")                                                                 \
        for (int nt = 0; nt < 9; ++nt)                                                    \
            acc[nt] = __builtin_amdgcn_mfma_f32_16x16x32_bf16(                            \
                af_.v, *(const bf16x8*)(bp_ + nt * 4096), acc[nt], 0, 0, 0);              \
    } while (0)

#define PHASE(C0, C1, C2, C3, C4, C5, C6, C7, N0, N1, N2, N3, N4, N5, N6, N7, P)          \
    do {                                                                                  \
        __syncthreads();                                                                  \
        DMA9(P);                                                                          \
        asm volatile("s_waitcnt vmcnt(0)" ::: "memory");                                  \
        __syncthreads();                                                                  \
        { const int pn_ = ((P) + 1 < NPH) ? (P) + 1 : NPH - 1;                            \
          LOADA(N0, N1, N2, N3, N4, N5, N6, N7, pn_); }                                   \
        CHUNKC(C0, C1, 0); CHUNKC(C2, C3, 1); CHUNKC(C4, C5, 2); CHUNKC(C6, C7, 3);       \
    } while (0)

    float4 e0, e1, e2, e3, e4, e5, e6, e7;
    float4 o0, o1, o2, o3, o4, o5, o6, o7;
    LOADA(e0, e1, e2, e3, e4, e5, e6, e7, 0);
    #pragma unroll 1
    for (int pp = 0; pp < 3; ++pp) {
        PHASE(e0, e1, e2, e3, e4, e5, e6, e7, o0, o1, o2, o3, o4, o5, o6, o7, 2 * pp);
        PHASE(o0, o1, o2, o3, o4, o5, o6, o7, e0, e1, e2, e3, e4, e5, e6, e7, 2 * pp + 1);
    }
#undef PHASE
#undef CHUNKC
#undef LOADA
#undef DMA9

    // epilogue: +bias, bf16 store [b][s][t], t-contiguous ushort4 per lane
    const int tq = tb + wv * 16 + g * 4;               // D row = g*4 + i
    #pragma unroll
    for (int nt = 0; nt < 9; ++nt) {
        int s = nt * 16 + r16;                          // D col = r16
        if (s < SS) {
            float bs = bias[s];
            ushort4 v;
            v.x = (unsigned short)f2bf(acc[nt][0] + bs);
            v.y = (unsigned short)f2bf(acc[nt][1] + bs);
            v.z = (unsigned short)f2bf(acc[nt][2] + bs);
            v.w = (unsigned short)f2bf(acc[nt][3] + bs);
            *(ushort4*)(logits + ((size_t)b * SS + s) * TT + tq) = v;
        }
    }
}

// ---- K2: barrier-free ragged segment-mean (bf16 logits -> f32 out) ----
__global__ __launch_bounds__(256)
void merge_kernel(const int2* __restrict__ bounds,
                  const unsigned short* __restrict__ logits,
                  float* __restrict__ out)
{
    const int blk = blockIdx.x;          // 256 * 65
    const int b   = blk / 65;
    const int sp  = (blk - b * 65) * 2;
    const int w   = threadIdx.x;

    const int2 bc = bounds[b * TT + w];  // {start, count}
    const float inv = (bc.y > 0) ? 1.f / (float)bc.y : 0.f;

    #pragma unroll
    for (int i = 0; i < 2; ++i) {
        const int s = sp + i;            // 130 = 65*2, always valid
        const unsigned short* row = logits + ((size_t)b * SS + s) * TT;
        float a = 0.f;
        for (int k = 0; k < bc.y; ++k) a += bf2f(row[bc.x + k]);
        out[((size_t)b * SS + s) * TT + w] = a * inv;
    }
}

extern "C" void kernel_launch(void* const* d_in, const int* in_sizes, int n_in,
                              void* d_out, int out_size, void* d_ws, size_t ws_size,
                              hipStream_t stream)
{
    const float* hidden = (const float*)d_in[0];  // [256, 257, 768] f32
    const float* W      = (const float*)d_in[1];  // [768, 130] f32
    const float* bias   = (const float*)d_in[2];  // [130] f32
    const int*   seg    = (const int*)d_in[3];    // [256, 256] i32 (row-sorted)
    float* out = (float*)d_out;                   // [256, 130, 256] f32

    unsigned*       wsT2   = (unsigned*)d_ws;                        // 221184 B
    int2*           bounds = (int2*)((char*)d_ws + 221184);          // 524288 B
    unsigned short* logits = (unsigned short*)((char*)d_ws + 221184 + 524288);  // 17039360 B

    (void)in_sizes; (void)n_in; (void)ws_size; (void)out_size;

    prep_kernel<<<dim3(310), dim3(256), 0, stream>>>(W, wsT2, seg, bounds);
    gemm_kernel<<<dim3(BB * 4), dim3(256), 0, stream>>>(hidden, wsT2, bias, logits);
    merge_kernel<<<dim3(BB * 65), dim3(256), 0, stream>>>(bounds, logits, out);
}